// Round 2
// baseline (273.767 us; speedup 1.0000x reference)
//
#include <hip/hip_runtime.h>

#define B_ 128
#define N_ 256
#define M_ 1024
#define EPS_ 1e-16f
#define NORM_EPS_ 1e-8f

// pass-3 n-split: blocks per batch row
#define SPLIT_ 8
#define NSUB_ (N_ / SPLIT_)

__device__ __forceinline__ float wave_reduce_sum(float v) {
#pragma unroll
    for (int off = 32; off; off >>= 1) v += __shfl_xor(v, off, 64);
    return v;
}

__device__ __forceinline__ float wave_reduce_max(float v) {
#pragma unroll
    for (int off = 32; off; off >>= 1) v = fmaxf(v, __shfl_xor(v, off, 64));
    return v;
}

// ---------------- Pass 1: per-row dot(mem+eps, k+eps) and ||mem+eps||^2 ----------------
// grid: (B*N)/4 blocks, 256 threads (4 waves, one wave per row)
__global__ void sim_kernel(const float* __restrict__ memory,
                           const float* __restrict__ k,
                           float* __restrict__ dot_out,
                           float* __restrict__ mnorm2_out) {
    const int wave = threadIdx.x >> 6;
    const int lane = threadIdx.x & 63;
    const int row  = blockIdx.x * 4 + wave;        // [0, B*N)
    const int b    = row >> 8;                     // N = 256

    const float4* __restrict__ mrow = (const float4*)(memory + (size_t)row * M_);
    const float4* __restrict__ krow = (const float4*)(k + (size_t)b * M_);

    float dacc = 0.f, nacc = 0.f;
#pragma unroll
    for (int it = 0; it < 4; ++it) {
        const int idx = it * 64 + lane;            // float4 index in [0,256)
        float4 mv = mrow[idx];
        float4 kv = krow[idx];
        float m0 = mv.x + EPS_, m1 = mv.y + EPS_, m2 = mv.z + EPS_, m3 = mv.w + EPS_;
        float k0 = kv.x + EPS_, k1 = kv.y + EPS_, k2 = kv.z + EPS_, k3 = kv.w + EPS_;
        dacc += m0 * k0 + m1 * k1 + m2 * k2 + m3 * k3;
        nacc += m0 * m0 + m1 * m1 + m2 * m2 + m3 * m3;
    }
    dacc = wave_reduce_sum(dacc);
    nacc = wave_reduce_sum(nacc);
    if (lane == 0) {
        dot_out[row]    = dacc;
        mnorm2_out[row] = nacc;
    }
}

// ---------------- Pass 2: per-b weight pipeline ----------------
// grid: B blocks, 256 threads (one per n). Also zero-inits read_out row.
__global__ void weight_kernel(const float* __restrict__ k,
                              const float* __restrict__ beta,
                              const float* __restrict__ g,
                              const float* __restrict__ s,
                              const float* __restrict__ gamma,
                              const float* __restrict__ w_prev,
                              const float* __restrict__ dot_in,
                              const float* __restrict__ mnorm2_in,
                              float* __restrict__ w_out,
                              float* __restrict__ read_out) {
    const int b    = blockIdx.x;
    const int tid  = threadIdx.x;                  // 0..255
    const int lane = tid & 63;
    const int wave = tid >> 6;

    __shared__ float red[4];
    __shared__ float s_wg[N_];

    // zero-init the read output row (d_out is poisoned before each launch)
    float4 z = {0.f, 0.f, 0.f, 0.f};
    ((float4*)(read_out + (size_t)b * M_))[tid] = z;

    // ---- knorm = max(||k+eps||, 1e-8) ----
    float4 kv = ((const float4*)(k + (size_t)b * M_))[tid];
    float k0 = kv.x + EPS_, k1 = kv.y + EPS_, k2 = kv.z + EPS_, k3 = kv.w + EPS_;
    float kk = k0 * k0 + k1 * k1 + k2 * k2 + k3 * k3;
    kk = wave_reduce_sum(kk);
    if (lane == 0) red[wave] = kk;
    __syncthreads();
    float knorm = fmaxf(sqrtf(red[0] + red[1] + red[2] + red[3]), NORM_EPS_);
    __syncthreads();

    // ---- cosine + beta scale ----
    const int n = tid;
    const float mnorm = fmaxf(sqrtf(mnorm2_in[(size_t)b * N_ + n]), NORM_EPS_);
    const float cosv  = dot_in[(size_t)b * N_ + n] / (mnorm * knorm);
    const float x     = beta[b] * cosv;

    // ---- softmax over n ----
    float mx = wave_reduce_max(x);
    if (lane == 0) red[wave] = mx;
    __syncthreads();
    mx = fmaxf(fmaxf(red[0], red[1]), fmaxf(red[2], red[3]));
    __syncthreads();
    float ex = __expf(x - mx);
    float es = wave_reduce_sum(ex);
    if (lane == 0) red[wave] = es;
    __syncthreads();
    es = red[0] + red[1] + red[2] + red[3];
    __syncthreads();
    const float w_c = ex / es;

    // ---- interpolate ----
    const float gb  = g[b];
    const float w_g = gb * w_c + (1.f - gb) * w_prev[(size_t)b * N_ + n];
    s_wg[n] = w_g;
    __syncthreads();

    // ---- circular 3-tap shift: w_t[n] = s0*w[n-1] + s1*w[n] + s2*w[n+1] ----
    const float s0 = s[b * 3 + 0], s1 = s[b * 3 + 1], s2 = s[b * 3 + 2];
    const float w_t = s0 * s_wg[(n + N_ - 1) & (N_ - 1)]
                    + s1 * s_wg[n]
                    + s2 * s_wg[(n + 1) & (N_ - 1)];

    // ---- sharpen ----
    const float w_pow = powf(w_t, gamma[b]);
    float ps = wave_reduce_sum(w_pow);
    if (lane == 0) red[wave] = ps;
    __syncthreads();
    ps = red[0] + red[1] + red[2] + red[3];

    w_out[(size_t)b * N_ + n] = w_pow / (ps + EPS_);
}

// ---------------- Pass 3: write (erase/add) + fused read ----------------
// grid: B*SPLIT_ blocks (n split), 256 threads, float4 per thread over M
__global__ void write_read_kernel(const float* __restrict__ memory,
                                  const float* __restrict__ e,
                                  const float* __restrict__ a,
                                  const float* __restrict__ w,
                                  float* __restrict__ newmem_out,
                                  float* __restrict__ read_out) {
    const int b    = blockIdx.x / SPLIT_;
    const int part = blockIdx.x % SPLIT_;
    const int tid  = threadIdx.x;                  // 0..255, one float4 each

    __shared__ float s_w[NSUB_];
    if (tid < NSUB_) s_w[tid] = w[(size_t)b * N_ + part * NSUB_ + tid];
    __syncthreads();

    const float4 ev = ((const float4*)(e + (size_t)b * M_))[tid];
    const float4 av = ((const float4*)(a + (size_t)b * M_))[tid];

    const size_t base = (size_t)b * N_ * M_;
    float4 racc = {0.f, 0.f, 0.f, 0.f};

#pragma unroll 4
    for (int j = 0; j < NSUB_; ++j) {
        const int n = part * NSUB_ + j;
        const float4 mv = ((const float4*)(memory + base + (size_t)n * M_))[tid];
        const float wn = s_w[j];
        float4 nv;
        nv.x = mv.x * (1.f - wn * ev.x) + wn * av.x;
        nv.y = mv.y * (1.f - wn * ev.y) + wn * av.y;
        nv.z = mv.z * (1.f - wn * ev.z) + wn * av.z;
        nv.w = mv.w * (1.f - wn * ev.w) + wn * av.w;
        ((float4*)(newmem_out + base + (size_t)n * M_))[tid] = nv;
        racc.x += wn * nv.x;
        racc.y += wn * nv.y;
        racc.z += wn * nv.z;
        racc.w += wn * nv.w;
    }

    float* rrow = read_out + (size_t)b * M_ + tid * 4;
    atomicAdd(rrow + 0, racc.x);
    atomicAdd(rrow + 1, racc.y);
    atomicAdd(rrow + 2, racc.z);
    atomicAdd(rrow + 3, racc.w);
}

extern "C" void kernel_launch(void* const* d_in, const int* in_sizes, int n_in,
                              void* d_out, int out_size, void* d_ws, size_t ws_size,
                              hipStream_t stream) {
    (void)in_sizes; (void)n_in; (void)out_size; (void)ws_size;

    const float* memory = (const float*)d_in[0];
    const float* k      = (const float*)d_in[1];
    const float* beta   = (const float*)d_in[2];
    const float* g      = (const float*)d_in[3];
    const float* s      = (const float*)d_in[4];
    const float* gamma  = (const float*)d_in[5];
    const float* w_prev = (const float*)d_in[6];
    const float* e      = (const float*)d_in[7];
    const float* a      = (const float*)d_in[8];

    float* out        = (float*)d_out;
    float* read_out   = out;                                 // B*M
    float* newmem_out = out + (size_t)B_ * M_;               // B*N*M
    float* w_out      = newmem_out + (size_t)B_ * N_ * M_;   // B*N

    float* ws        = (float*)d_ws;
    float* dot_ws    = ws;                                   // B*N
    float* mnorm2_ws = ws + (size_t)B_ * N_;                 // B*N

    sim_kernel<<<(B_ * N_) / 4, 256, 0, stream>>>(memory, k, dot_ws, mnorm2_ws);
    weight_kernel<<<B_, 256, 0, stream>>>(k, beta, g, s, gamma, w_prev,
                                          dot_ws, mnorm2_ws, w_out, read_out);
    write_read_kernel<<<B_ * SPLIT_, 256, 0, stream>>>(memory, e, a, w_out,
                                                       newmem_out, read_out);
}